// Round 1
// 416.213 us; speedup vs baseline: 1.0209x; 1.0209x over previous
//
#include <hip/hip_runtime.h>
#include <stdint.h>
#include <stddef.h>

typedef __attribute__((ext_vector_type(8))) short short8;
typedef __attribute__((ext_vector_type(4))) float floatx4;

#define MFMA_BF16(A, B, C) __builtin_amdgcn_mfma_f32_16x16x32_bf16((A), (B), (C), 0, 0, 0)

static constexpr int NB   = 32768;
static constexpr int LV   = 1024;   // L, and folded K1
static constexpr int HIDV = 256;
static constexpr int OUTV = 1024;
static constexpr size_t HOFF = (size_t)NB * OUTV;  // d_out = [fund | h]

__device__ __forceinline__ short f2bf(float f) {
  union { float f; uint32_t u; } c; c.f = f;
  uint32_t u = c.u;
  u += 0x7fffu + ((u >> 16) & 1u);   // RNE to bf16
  return (short)(u >> 16);
}

// Merged weight prep (one launch instead of two).
// idx < 256*1024: W1eff fold -> w1bf ; else: W2 cast -> w2bf.
// W1eff[n][k] = W1[n][k] + [k<341]*W1[n][1024+k] + [k<682]*0.5*W1[n][1024+k/2]
//            + [k<1023]*(1/3)*W1[n][1024+k/3]   (pooling folded into weights)
__global__ __launch_bounds__(256) void wprep(const float* __restrict__ W1,
                                             const float* __restrict__ W2,
                                             short* __restrict__ w1bf,
                                             short* __restrict__ w2bf) {
  int idx = blockIdx.x * 256 + threadIdx.x;   // grid = 2048 blocks
  if (idx < 256 * 1024) {
    int n = idx >> 10;
    int k = idx & 1023;
    const float* r = W1 + (size_t)n * 1365;
    float v = r[k];
    if (k < 341)  v += r[1024 + k];
    if (k < 682)  v += 0.5f * r[1024 + (k >> 1)];
    if (k < 1023) v += (1.f / 3.f) * r[1024 + k / 3];
    w1bf[idx] = f2bf(v);
  } else {
    int j = idx - 256 * 1024;
    w2bf[j] = f2bf(W2[j]);
  }
}

// Fused: h-copy + GEMM1(relu, K=1024) + GEMM2(K=256), M-tile=64, 8 waves.
// Sync structure: raw s_barrier with writer-side lgkmcnt(0) ONLY (no vmcnt
// drain — all global ops are wave-private: x loads, h/fund stores, L2 B
// loads). h-stores + next-tile loads issued AFTER the barrier so their
// latency hides under the MFMA/LDS phase instead of being drained at it.
__global__ __launch_bounds__(512, 4) void gemm_fused(
    const float* __restrict__ x,
    const short* __restrict__ w1bf, const short* __restrict__ w2bf,
    const float* __restrict__ b1, const float* __restrict__ b2,
    float* __restrict__ out) {
  // row stride 72 shorts (144 B): /16B = 9 (odd) -> balanced bank groups for b128
  __shared__ __align__(16) short Abuf[2][64 * 72];
  // row stride 264 shorts (528 B): /16B = 33 (odd) -> balanced
  __shared__ __align__(16) short Hbuf[64 * 264];

  const int tid  = threadIdx.x;
  const int wave = tid >> 6;
  const int lane = tid & 63;
  const int l15  = lane & 15;
  const int quad = lane >> 4;
  const int row0 = blockIdx.x * 64;

  const int srow = tid >> 3;   // staging row 0..63
  const int sseg = tid & 7;    // staging segment 0..7 (8 fp32 each)

  float4 xa, xb;
  const floatx4 fzero = {0.f, 0.f, 0.f, 0.f};

  const float4* xrow = reinterpret_cast<const float4*>(x + (size_t)(row0 + srow) * LV);
  float4* hrow = reinterpret_cast<float4*>(out + HOFF + (size_t)(row0 + srow) * LV);

  auto loadA = [&](int ck) {
    xa = xrow[ck * 16 + 2 * sseg];
    xb = xrow[ck * 16 + 2 * sseg + 1];
  };
  auto writeA = [&](int buf) {      // LDS only — the op the barrier must order
    short8 p;
    p[0] = f2bf(xa.x); p[1] = f2bf(xa.y); p[2] = f2bf(xa.z); p[3] = f2bf(xa.w);
    p[4] = f2bf(xb.x); p[5] = f2bf(xb.y); p[6] = f2bf(xb.z); p[7] = f2bf(xb.w);
    *reinterpret_cast<short8*>(&Abuf[buf][srow * 72 + sseg * 8]) = p;
  };
  auto storeH = [&](int ck) {       // global, wave-private: issued post-barrier
    hrow[ck * 16 + 2 * sseg]     = xa;
    hrow[ck * 16 + 2 * sseg + 1] = xb;
  };

  short8 Breg[4], Bnxt[4];   // [ks*2+ns]
  auto loadB1 = [&](int ck, short8* dst) {
    #pragma unroll
    for (int ks = 0; ks < 2; ++ks)
      #pragma unroll
      for (int ns = 0; ns < 2; ++ns)
        dst[ks * 2 + ns] = *reinterpret_cast<const short8*>(
            w1bf + (size_t)(wave * 32 + ns * 16 + l15) * LV + ck * 64 + ks * 32 + quad * 8);
  };

  floatx4 acc1[4][2];
  #pragma unroll
  for (int ms = 0; ms < 4; ++ms)
    #pragma unroll
    for (int ns = 0; ns < 2; ++ns)
      acc1[ms][ns] = fzero;

  loadA(0);
  loadB1(0, Breg);

  #pragma unroll 1
  for (int ck = 0; ck < 16; ++ck) {
    const int buf = ck & 1;
    writeA(buf);
    // writer-side LDS drain + raw barrier: vmcnt ops stay in flight
    asm volatile("s_waitcnt lgkmcnt(0)" ::: "memory");
    __builtin_amdgcn_s_barrier();
    asm volatile("" ::: "memory");
    storeH(ck);                                   // hides under MFMA phase
    if (ck < 15) { loadA(ck + 1); loadB1(ck + 1, Bnxt); }
    #pragma unroll
    for (int ks = 0; ks < 2; ++ks) {
      short8 afr[4];
      #pragma unroll
      for (int ms = 0; ms < 4; ++ms)
        afr[ms] = *reinterpret_cast<const short8*>(
            &Abuf[buf][(ms * 16 + l15) * 72 + ks * 32 + quad * 8]);
      #pragma unroll
      for (int ms = 0; ms < 4; ++ms)
        #pragma unroll
        for (int ns = 0; ns < 2; ++ns)
          acc1[ms][ns] = MFMA_BF16(afr[ms], Breg[ks * 2 + ns], acc1[ms][ns]);
    }
    #pragma unroll
    for (int i = 0; i < 4; ++i) Breg[i] = Bnxt[i];
  }

  // GEMM1 epilogue: bias + relu -> bf16 Hbuf (C-layout: row = quad*4+r, col = l15)
  #pragma unroll
  for (int ms = 0; ms < 4; ++ms) {
    #pragma unroll
    for (int ns = 0; ns < 2; ++ns) {
      const int n = wave * 32 + ns * 16 + l15;
      const float bias = b1[n];
      #pragma unroll
      for (int r = 0; r < 4; ++r) {
        const int m = ms * 16 + quad * 4 + r;
        float v = acc1[ms][ns][r] + bias;
        Hbuf[m * 264 + n] = f2bf(v > 0.f ? v : 0.f);
      }
    }
  }
  asm volatile("s_waitcnt lgkmcnt(0)" ::: "memory");
  __builtin_amdgcn_s_barrier();
  asm volatile("" ::: "memory");

  // GEMM2: K=256 from Hbuf, 4 sequential N-quarters of 256, cross-q B prefetch
  short8 B2[2], B2n[2];
  auto loadB2 = [&](int q, int kc, short8* dst) {
    #pragma unroll
    for (int ns = 0; ns < 2; ++ns)
      dst[ns] = *reinterpret_cast<const short8*>(
          w2bf + (size_t)(q * 256 + wave * 32 + ns * 16 + l15) * HIDV + kc * 32 + quad * 8);
  };

  loadB2(0, 0, B2);
  #pragma unroll 1
  for (int q = 0; q < 4; ++q) {
    floatx4 acc2[4][2];
    #pragma unroll
    for (int ms = 0; ms < 4; ++ms)
      #pragma unroll
      for (int ns = 0; ns < 2; ++ns)
        acc2[ms][ns] = fzero;
    #pragma unroll 1
    for (int kc = 0; kc < 8; ++kc) {
      short8 afr[4];
      #pragma unroll
      for (int ms = 0; ms < 4; ++ms)
        afr[ms] = *reinterpret_cast<const short8*>(
            &Hbuf[(ms * 16 + l15) * 264 + kc * 32 + quad * 8]);
      const int t = q * 8 + kc + 1;        // flattened next (q,kc) — crosses q
      if (t < 32) loadB2(t >> 3, t & 7, B2n);
      #pragma unroll
      for (int ms = 0; ms < 4; ++ms)
        #pragma unroll
        for (int ns = 0; ns < 2; ++ns)
          acc2[ms][ns] = MFMA_BF16(afr[ms], B2[ns], acc2[ms][ns]);
      #pragma unroll
      for (int i = 0; i < 2; ++i) B2[i] = B2n[i];
    }
    #pragma unroll
    for (int ms = 0; ms < 4; ++ms) {
      #pragma unroll
      for (int ns = 0; ns < 2; ++ns) {
        const int o = q * 256 + wave * 32 + ns * 16 + l15;
        const float bias = b2[o];
        #pragma unroll
        for (int r = 0; r < 4; ++r) {
          const int m = ms * 16 + quad * 4 + r;
          out[(size_t)(row0 + m) * OUTV + o] = acc2[ms][ns][r] + bias;
        }
      }
    }
  }
}

extern "C" void kernel_launch(void* const* d_in, const int* in_sizes, int n_in,
                              void* d_out, int out_size, void* d_ws, size_t ws_size,
                              hipStream_t stream) {
  const float* x  = (const float*)d_in[0];
  const float* W1 = (const float*)d_in[1];
  const float* b1 = (const float*)d_in[2];
  const float* W2 = (const float*)d_in[3];
  const float* b2 = (const float*)d_in[4];
  float* out = (float*)d_out;

  char* ws = (char*)d_ws;
  short* w1bf = (short*)(ws);                // 256*1024*2  = 524,288 B
  short* w2bf = (short*)(ws + 524288);       // 1024*256*2  = 524,288 B

  hipLaunchKernelGGL(wprep, dim3(2048), dim3(256), 0, stream, W1, W2, w1bf, w2bf);
  hipLaunchKernelGGL(gemm_fused, dim3(NB / 64), dim3(512), 0, stream,
                     x, w1bf, w2bf, b1, b2, out);
}

// Round 2
// 412.962 us; speedup vs baseline: 1.0290x; 1.0079x over previous
//
#include <hip/hip_runtime.h>
#include <stdint.h>
#include <stddef.h>

typedef __attribute__((ext_vector_type(8))) short short8;
typedef __attribute__((ext_vector_type(4))) float floatx4;

#define MFMA_BF16(A, B, C) __builtin_amdgcn_mfma_f32_16x16x32_bf16((A), (B), (C), 0, 0, 0)

static constexpr int NB   = 32768;
static constexpr int LV   = 1024;   // L, and folded K1
static constexpr int HIDV = 256;
static constexpr int OUTV = 1024;
static constexpr size_t HOFF = (size_t)NB * OUTV;  // d_out = [fund | h]

__device__ __forceinline__ short f2bf(float f) {
  union { float f; uint32_t u; } c; c.f = f;
  uint32_t u = c.u;
  u += 0x7fffu + ((u >> 16) & 1u);   // RNE to bf16
  return (short)(u >> 16);
}

// Merged weight prep (one launch).
// idx < 256*1024: W1eff fold -> w1bf ; else: W2 cast -> w2bf.
// W1eff[n][k] = W1[n][k] + [k<341]*W1[n][1024+k] + [k<682]*0.5*W1[n][1024+k/2]
//            + [k<1023]*(1/3)*W1[n][1024+k/3]   (pooling folded into weights)
__global__ __launch_bounds__(256) void wprep(const float* __restrict__ W1,
                                             const float* __restrict__ W2,
                                             short* __restrict__ w1bf,
                                             short* __restrict__ w2bf) {
  int idx = blockIdx.x * 256 + threadIdx.x;   // grid = 2048 blocks
  if (idx < 256 * 1024) {
    int n = idx >> 10;
    int k = idx & 1023;
    const float* r = W1 + (size_t)n * 1365;
    float v = r[k];
    if (k < 341)  v += r[1024 + k];
    if (k < 682)  v += 0.5f * r[1024 + (k >> 1)];
    if (k < 1023) v += (1.f / 3.f) * r[1024 + k / 3];
    w1bf[idx] = f2bf(v);
  } else {
    int j = idx - 256 * 1024;
    w2bf[j] = f2bf(W2[j]);
  }
}

// Fused: h-copy + GEMM1(relu, K=1024) + GEMM2(K=256), M-tile=64, 8 waves.
// Sync: raw s_barrier + writer-side lgkmcnt(0) only (no vmcnt drain).
// Depth-2 x-prefetch (2 named reg tile-pairs, static parity via manual 2x
// unroll). Per-iter VMEM issue order: loadB1(next) -> storeH(cur) ->
// loadA(cur+2), so waits on B/A never chain behind store acks (vmcnt FIFO
// is in-order). Stream-once traffic (x, h, fund) is nontemporal.
__global__ __launch_bounds__(512, 4) void gemm_fused(
    const float* __restrict__ x,
    const short* __restrict__ w1bf, const short* __restrict__ w2bf,
    const float* __restrict__ b1, const float* __restrict__ b2,
    float* __restrict__ out) {
  // row stride 72 shorts (144 B): /16B = 9 (odd) -> balanced bank groups for b128
  __shared__ __align__(16) short Abuf[2][64 * 72];
  // row stride 264 shorts (528 B): /16B = 33 (odd) -> balanced
  __shared__ __align__(16) short Hbuf[64 * 264];

  const int tid  = threadIdx.x;
  const int wave = tid >> 6;
  const int lane = tid & 63;
  const int l15  = lane & 15;
  const int quad = lane >> 4;
  const int row0 = blockIdx.x * 64;

  const int srow = tid >> 3;   // staging row 0..63
  const int sseg = tid & 7;    // staging segment 0..7 (8 fp32 each)

  const floatx4 fzero = {0.f, 0.f, 0.f, 0.f};

  const floatx4* xrow = reinterpret_cast<const floatx4*>(x + (size_t)(row0 + srow) * LV);
  floatx4* hrow = reinterpret_cast<floatx4*>(out + HOFF + (size_t)(row0 + srow) * LV);

  floatx4 xa0, xb0, xa1, xb1;   // depth-2 prefetch: parity-named (no dyn index)

  auto loadA = [&](int ck, floatx4& a, floatx4& b) {
    a = __builtin_nontemporal_load(xrow + ck * 16 + 2 * sseg);
    b = __builtin_nontemporal_load(xrow + ck * 16 + 2 * sseg + 1);
  };
  auto writeA = [&](int buf, const floatx4& a, const floatx4& b) {  // LDS only
    short8 p;
    p[0] = f2bf(a[0]); p[1] = f2bf(a[1]); p[2] = f2bf(a[2]); p[3] = f2bf(a[3]);
    p[4] = f2bf(b[0]); p[5] = f2bf(b[1]); p[6] = f2bf(b[2]); p[7] = f2bf(b[3]);
    *reinterpret_cast<short8*>(&Abuf[buf][srow * 72 + sseg * 8]) = p;
  };
  auto storeH = [&](int ck, const floatx4& a, const floatx4& b) {  // global, wave-private
    __builtin_nontemporal_store(a, hrow + ck * 16 + 2 * sseg);
    __builtin_nontemporal_store(b, hrow + ck * 16 + 2 * sseg + 1);
  };

  short8 Breg[4], Bnxt[4];   // [ks*2+ns]
  auto loadB1 = [&](int ck, short8* dst) {
    #pragma unroll
    for (int ks = 0; ks < 2; ++ks)
      #pragma unroll
      for (int ns = 0; ns < 2; ++ns)
        dst[ks * 2 + ns] = *reinterpret_cast<const short8*>(
            w1bf + (size_t)(wave * 32 + ns * 16 + l15) * LV + ck * 64 + ks * 32 + quad * 8);
  };

  floatx4 acc1[4][2];
  #pragma unroll
  for (int ms = 0; ms < 4; ++ms)
    #pragma unroll
    for (int ns = 0; ns < 2; ++ns)
      acc1[ms][ns] = fzero;

  loadA(0, xa0, xb0);
  loadA(1, xa1, xb1);
  loadB1(0, Breg);

  auto kstep = [&](int ck, int buf, floatx4& a, floatx4& b) {
    writeA(buf, a, b);
    asm volatile("s_waitcnt lgkmcnt(0)" ::: "memory");
    __builtin_amdgcn_s_barrier();
    asm volatile("" ::: "memory");
    if (ck + 1 < 16) loadB1(ck + 1, Bnxt);   // needed next iter: issue first
    storeH(ck, a, b);                        // must read P before refill
    if (ck + 2 < 16) loadA(ck + 2, a, b);    // needed in 2 iters: issue last
    #pragma unroll
    for (int ks = 0; ks < 2; ++ks) {
      short8 afr[4];
      #pragma unroll
      for (int ms = 0; ms < 4; ++ms)
        afr[ms] = *reinterpret_cast<const short8*>(
            &Abuf[buf][(ms * 16 + l15) * 72 + ks * 32 + quad * 8]);
      #pragma unroll
      for (int ms = 0; ms < 4; ++ms)
        #pragma unroll
        for (int ns = 0; ns < 2; ++ns)
          acc1[ms][ns] = MFMA_BF16(afr[ms], Breg[ks * 2 + ns], acc1[ms][ns]);
    }
    #pragma unroll
    for (int i = 0; i < 4; ++i) Breg[i] = Bnxt[i];
  };

  #pragma unroll 1
  for (int ck2 = 0; ck2 < 16; ck2 += 2) {
    kstep(ck2,     0, xa0, xb0);
    kstep(ck2 + 1, 1, xa1, xb1);
  }

  // GEMM1 epilogue: bias + relu -> bf16 Hbuf (C-layout: row = quad*4+r, col = l15)
  #pragma unroll
  for (int ms = 0; ms < 4; ++ms) {
    #pragma unroll
    for (int ns = 0; ns < 2; ++ns) {
      const int n = wave * 32 + ns * 16 + l15;
      const float bias = b1[n];
      #pragma unroll
      for (int r = 0; r < 4; ++r) {
        const int m = ms * 16 + quad * 4 + r;
        float v = acc1[ms][ns][r] + bias;
        Hbuf[m * 264 + n] = f2bf(v > 0.f ? v : 0.f);
      }
    }
  }
  asm volatile("s_waitcnt lgkmcnt(0)" ::: "memory");
  __builtin_amdgcn_s_barrier();
  asm volatile("" ::: "memory");

  // GEMM2: K=256 from Hbuf, 4 sequential N-quarters of 256, cross-q B prefetch
  short8 B2[2], B2n[2];
  auto loadB2 = [&](int q, int kc, short8* dst) {
    #pragma unroll
    for (int ns = 0; ns < 2; ++ns)
      dst[ns] = *reinterpret_cast<const short8*>(
          w2bf + (size_t)(q * 256 + wave * 32 + ns * 16 + l15) * HIDV + kc * 32 + quad * 8);
  };

  loadB2(0, 0, B2);
  #pragma unroll 1
  for (int q = 0; q < 4; ++q) {
    floatx4 acc2[4][2];
    #pragma unroll
    for (int ms = 0; ms < 4; ++ms)
      #pragma unroll
      for (int ns = 0; ns < 2; ++ns)
        acc2[ms][ns] = fzero;
    #pragma unroll 1
    for (int kc = 0; kc < 8; ++kc) {
      short8 afr[4];
      #pragma unroll
      for (int ms = 0; ms < 4; ++ms)
        afr[ms] = *reinterpret_cast<const short8*>(
            &Hbuf[(ms * 16 + l15) * 264 + kc * 32 + quad * 8]);
      const int t = q * 8 + kc + 1;        // flattened next (q,kc) — crosses q
      if (t < 32) loadB2(t >> 3, t & 7, B2n);
      #pragma unroll
      for (int ms = 0; ms < 4; ++ms)
        #pragma unroll
        for (int ns = 0; ns < 2; ++ns)
          acc2[ms][ns] = MFMA_BF16(afr[ms], B2[ns], acc2[ms][ns]);
      #pragma unroll
      for (int i = 0; i < 2; ++i) B2[i] = B2n[i];
    }
    #pragma unroll
    for (int ms = 0; ms < 4; ++ms) {
      #pragma unroll
      for (int ns = 0; ns < 2; ++ns) {
        const int o = q * 256 + wave * 32 + ns * 16 + l15;
        const float bias = b2[o];
        #pragma unroll
        for (int r = 0; r < 4; ++r) {
          const int m = ms * 16 + quad * 4 + r;
          __builtin_nontemporal_store(acc2[ms][ns][r] + bias,
                                      &out[(size_t)(row0 + m) * OUTV + o]);
        }
      }
    }
  }
}

extern "C" void kernel_launch(void* const* d_in, const int* in_sizes, int n_in,
                              void* d_out, int out_size, void* d_ws, size_t ws_size,
                              hipStream_t stream) {
  const float* x  = (const float*)d_in[0];
  const float* W1 = (const float*)d_in[1];
  const float* b1 = (const float*)d_in[2];
  const float* W2 = (const float*)d_in[3];
  const float* b2 = (const float*)d_in[4];
  float* out = (float*)d_out;

  char* ws = (char*)d_ws;
  short* w1bf = (short*)(ws);                // 256*1024*2  = 524,288 B
  short* w2bf = (short*)(ws + 524288);       // 1024*256*2  = 524,288 B

  hipLaunchKernelGGL(wprep, dim3(2048), dim3(256), 0, stream, W1, W2, w1bf, w2bf);
  hipLaunchKernelGGL(gemm_fused, dim3(NB / 64), dim3(512), 0, stream,
                     x, w1bf, w2bf, b1, b2, out);
}